// Round 7
// baseline (86.500 us; speedup 1.0000x reference)
//
#include <hip/hip_runtime.h>
#include <hip/hip_fp16.h>

// ElementalGTOLogNormalSkinCutoff on MI355X (gfx950) — round 7
//
// Round-5 structure (best: APB=16, 320 thr, 1024 blocks, thread=(atom,g),
// 4 species-sorted LDS segments, Horner-in-exp2 radial, x2 unroll) with:
//  * 16-byte packed record {half2(c0,c1), f32 c2, half2(ux,uy), half2(uz,_)}
//    -> ONE ds_read_b128 per (neighbour,g) instead of b128+b64. LDS-issue
//    was the phase-2 bottleneck (~18 cyc/iter-wave at the shared LDS unit);
//    now ~12, with +6 cvt VALU (~11.5 cyc/CU) — pipes balanced.
//    Precision: half on (c0,c1) perturbs the exponent <=0.006 for dominant
//    neighbours (d in [1,3]); far ones are cutoff-damped. Threshold 103.68.
//  * Two-pass phase 1 (count species, then build straight into sorted slot)
//    — no register record buffers, same 1024-block grid as round 5.

#define B_   128
#define N_   128
#define M_   64
#define NG_  20
#define NSP_ 4
#define FPSIZE_ 600
#define APB  16                     // atoms per block (divides N_, so b uniform)
#define NTASK (APB * M_)            // 1024 neighbour slots per block
#define BLOCK_THREADS (APB * NG_)   // 320 = 5 waves

__global__ __launch_bounds__(BLOCK_THREADS)
void gto_fp_kernel(const float* __restrict__ coords,   // [B,N,3]
                   const int*   __restrict__ charges,  // [B,N]
                   const int*   __restrict__ counts,   // [B]
                   const int*   __restrict__ neigh,    // [B,N,M]
                   float*       __restrict__ out)      // [B,N,600]
{
    __shared__ float4 sR[APB][M_ + 1];      // packed record (padded row)
    __shared__ int s_cnt[APB][NSP_];
    __shared__ int s_start[APB][NSP_];
    __shared__ int s_pos[APB][NSP_];

    const int tid = threadIdx.x;
    const int blockBase = blockIdx.x * APB;
    const int bidx = blockBase / N_;        // uniform: APB divides N_

    if (tid < APB * NSP_) ((int*)s_cnt)[tid] = 0;
    __syncthreads();

    // -------- phase 1a: count species per atom (neigh + charge only) ------
    for (int t = tid; t < NTASK; t += BLOCK_THREADS) {
        const int la = t >> 6, m = t & 63;
        const int nb = neigh[(blockBase + la) * M_ + m];
        if (nb >= 0) {
            const int z = charges[bidx * N_ + nb];
            const int s = (z == 1) ? 0 : (z - 5);   // {1,6,7,8} -> {0,1,2,3}
            atomicAdd(&s_cnt[la][s], 1);
        }
    }
    __syncthreads();

    if (tid < APB) {
        const int c0 = s_cnt[tid][0], c1 = s_cnt[tid][1], c2 = s_cnt[tid][2];
        s_start[tid][0] = 0;            s_pos[tid][0] = 0;
        s_start[tid][1] = c0;           s_pos[tid][1] = c0;
        s_start[tid][2] = c0 + c1;      s_pos[tid][2] = c0 + c1;
        s_start[tid][3] = c0 + c1 + c2; s_pos[tid][3] = c0 + c1 + c2;
    }
    __syncthreads();

    // -------- phase 1b: build packed records into sorted slots ------------
    for (int t = tid; t < NTASK; t += BLOCK_THREADS) {
        const int la = t >> 6, m = t & 63;
        const int atom = blockBase + la;
        const int nb = neigh[atom * M_ + m];
        if (nb < 0) continue;
        const int nidx = bidx * N_ + nb;
        const float dx = coords[atom * 3 + 0] - coords[nidx * 3 + 0];
        const float dy = coords[atom * 3 + 1] - coords[nidx * 3 + 1];
        const float dz = coords[atom * 3 + 2] - coords[nidx * 3 + 2];
        const int   z  = charges[nidx];

        const float d2     = dx * dx + dy * dy + dz * dz;
        const float inv_d  = __builtin_amdgcn_rsqf(d2);
        const float d      = d2 * inv_d;
        const float inv_d2 = inv_d * inv_d;

        const float dsw  = (d - 1.0f) * 0.2f;
        const float dsw2 = dsw * dsw;
        const float cut  = 1.0f - dsw2 * dsw * fmaf(6.0f, dsw2, fmaf(-15.0f, dsw, 10.0f));

        const float sigma2 = __logf(fmaf(2.0f, inv_d2, 1.0f));     // log(1+W/d^2)
        const float mu     = 0.5f * (__logf(d2) - sigma2);         // log(d)-s2/2
        const float amp    = fmaxf(__builtin_amdgcn_rsqf(sigma2) * cut * inv_d2,
                                   1.0e-30f);   // cut can be ~-1e-7 at d~6

        const float F   = -0.72134752f * __builtin_amdgcn_rcpf(sigma2); // -0.5*log2e/s2
        const float Fm  = F * mu;
        const float c1v = -(Fm + Fm);
        const float c2v = fmaf(Fm, mu, __log2f(amp));

        const __half2 hc = __floats2half2_rn(F, c1v);
        const __half2 hu = __floats2half2_rn(dx * inv_d, dy * inv_d);
        const __half2 hw = __floats2half2_rn(dz * inv_d, 0.0f);
        float4 rec;
        rec.x = *(const float*)&hc;
        rec.y = c2v;
        rec.z = *(const float*)&hu;
        rec.w = *(const float*)&hw;

        const int s = (z == 1) ? 0 : (z - 5);
        const int slot = atomicAdd(&s_pos[la][s], 1);
        sR[la][slot] = rec;
    }
    __syncthreads();

    // -------- phase 2: thread = (atom, g); accumulate T[4][10] ------------
    const int g  = tid % NG_;
    const int la = tid / NG_;
    const int atom = blockBase + la;
    const int n = atom % N_;

    const float off = 0.3f * (float)(g + 1);
    const float lo  = __logf(off);
    const float lo2 = lo * lo;
    const float inv_off_spi = 1.0f / (off * 1.7724538509055159f);

    float T[NSP_][10];
#pragma unroll
    for (int s = 0; s < NSP_; ++s)
#pragma unroll
        for (int a = 0; a < 10; ++a) T[s][a] = 0.0f;

#define BODY(SS, R)                                                           \
    {                                                                         \
        const __half2 hc = *(const __half2*)&R.x;                             \
        const __half2 hu = *(const __half2*)&R.z;                             \
        const __half2 hw = *(const __half2*)&R.w;                             \
        const float c0 = __low2float(hc), c1 = __high2float(hc);              \
        const float ux = __low2float(hu), uy = __high2float(hu);              \
        const float uz = __low2float(hw);                                     \
        const float rad = __builtin_amdgcn_exp2f(                             \
            fmaf(c0, lo2, fmaf(c1, lo, R.y)));                                \
        const float rx = rad * ux, ry = rad * uy, rz = rad * uz;              \
        T[SS][0] += rad;                                                      \
        T[SS][1] += rx;  T[SS][2] += ry;  T[SS][3] += rz;                     \
        T[SS][4] = fmaf(rx, ux, T[SS][4]);                                    \
        T[SS][5] = fmaf(rx, uy, T[SS][5]);                                    \
        T[SS][6] = fmaf(ry, uy, T[SS][6]);                                    \
        T[SS][7] = fmaf(rx, uz, T[SS][7]);                                    \
        T[SS][8] = fmaf(ry, uz, T[SS][8]);                                    \
        T[SS][9] = fmaf(rz, uz, T[SS][9]);                                    \
    }

#define ACC(SS)                                                               \
    {                                                                         \
        const int e0 = s_start[la][SS];                                       \
        const int e1 = e0 + s_cnt[la][SS];                                    \
        int m = e0;                                                           \
        for (; m + 1 < e1; m += 2) {                                          \
            const float4 Ra = sR[la][m];                                      \
            const float4 Rb = sR[la][m + 1];                                  \
            BODY(SS, Ra)                                                      \
            BODY(SS, Rb)                                                      \
        }                                                                     \
        if (m < e1) {                                                         \
            const float4 Ra = sR[la][m];                                      \
            BODY(SS, Ra)                                                      \
        }                                                                     \
    }
    ACC(0) ACC(1) ACC(2) ACC(3)
#undef ACC
#undef BODY

    // -------- epilogue: 30 outputs for this g -----------------------------
    const float amask = (n < counts[bidx]) ? 1.0f : 0.0f;
    const float scale = amask * inv_off_spi * inv_off_spi;
    float* op = out + atom * FPSIZE_ + g;

    // angw = [1, 1,1,1, 1,2,1,2,2,1]; lw = 1 for all l
#pragma unroll
    for (int l = 0; l < 3; ++l) {
        const int a0 = (l == 0) ? 0 : (l == 1) ? 1 : 4;
        const int a1 = (l == 0) ? 1 : (l == 1) ? 4 : 10;
#pragma unroll
        for (int s = 0; s < NSP_; ++s) {
            float v = 0.0f;
#pragma unroll
            for (int a = a0; a < a1; ++a) {
                const float w = (a == 5 || a == 7 || a == 8) ? 2.0f : 1.0f;
                v = fmaf(w * T[s][a], T[s][a], v);
            }
            op[(l * 10 + s) * NG_] = scale * v;
        }
        int mb = 4;
#pragma unroll
        for (int i = 0; i < NSP_; ++i) {
#pragma unroll
            for (int j = i + 1; j < NSP_; ++j) {
                float v = 0.0f;
#pragma unroll
                for (int a = a0; a < a1; ++a) {
                    const float w = (a == 5 || a == 7 || a == 8) ? 2.0f : 1.0f;
                    v = fmaf(w * T[i][a], T[j][a], v);
                }
                op[(l * 10 + mb) * NG_] = scale * (2.0f * v);
                ++mb;
            }
        }
    }
}

extern "C" void kernel_launch(void* const* d_in, const int* in_sizes, int n_in,
                              void* d_out, int out_size, void* d_ws, size_t ws_size,
                              hipStream_t stream) {
    const float* coords  = (const float*)d_in[0];
    const int*   charges = (const int*)d_in[1];
    const int*   counts  = (const int*)d_in[2];
    const int*   neigh   = (const int*)d_in[3];
    float*       outp    = (float*)d_out;

    const int blocks = (B_ * N_) / APB;   // 1024
    gto_fp_kernel<<<blocks, BLOCK_THREADS, 0, stream>>>(coords, charges, counts, neigh, outp);
}